// Round 2
// baseline (291.505 us; speedup 1.0000x reference)
//
#include <hip/hip_runtime.h>
#include <stdint.h>

typedef __attribute__((ext_vector_type(8))) short  bf16x8;
typedef __attribute__((ext_vector_type(4))) float  f32x4;
typedef __attribute__((ext_vector_type(4))) int    int4v;
typedef __attribute__((ext_vector_type(4))) float  float4v;
typedef __attribute__((ext_vector_type(2))) unsigned int uint2v;

#define NN   8192   // nodes
#define DIN  512
#define DOUT 256

#define MFMA16(a, b, c) __builtin_amdgcn_mfma_f32_16x16x32_bf16((a), (b), (c), 0, 0, 0)

__device__ __forceinline__ unsigned short f2bf(float f) {
  unsigned u = __float_as_uint(f);
  return (unsigned short)((u + 0x7FFFu + ((u >> 16) & 1u)) >> 16);
}

// ---------------------------------------------------------------------------
// Kernel 0: Wt[n][c] = bf16(W[c][n]).  W: [512][256] f32 -> Wt: [256][512] bf16
// ---------------------------------------------------------------------------
__global__ void k_wt(const float* __restrict__ W, unsigned short* __restrict__ Wt) {
  int n = blockIdx.x; // 0..255
  for (int c = threadIdx.x; c < DIN; c += blockDim.x)
    Wt[n * DIN + c] = f2bf(W[c * DOUT + n]);
}

// ---------------------------------------------------------------------------
// Kernel 1: xw_t[n][m] = sum_c x[m][c] * W[c][n]   (bf16 out, transposed)
// ---------------------------------------------------------------------------
__global__ __launch_bounds__(256) void k_xwt(const float* __restrict__ x,
                                             const unsigned short* __restrict__ Wt,
                                             unsigned short* __restrict__ xw_t) {
  const int mb = blockIdx.x >> 1, nb = blockIdx.x & 1;
  const int tid = threadIdx.x;
  const int w = tid >> 6, l = tid & 63;
  const int wm = w >> 1, wn = w & 1;
  const int lr = l & 15, lg = l >> 4;
  const int m_base = mb * 128 + wm * 64;
  const int n_base = nb * 128 + wn * 64;

  f32x4 acc[4][4];
  for (int i = 0; i < 4; ++i)
    for (int j = 0; j < 4; ++j) acc[i][j] = (f32x4)0.0f;

  for (int c0 = 0; c0 < DIN; c0 += 32) {
    const int c = c0 + lg * 8;
    bf16x8 af[4], bfv[4];
#pragma unroll
    for (int mt = 0; mt < 4; ++mt) {
      const float* xp = x + (size_t)(m_base + mt * 16 + lr) * DIN + c;
      float4v x0 = *reinterpret_cast<const float4v*>(xp);
      float4v x1 = *reinterpret_cast<const float4v*>(xp + 4);
      bf16x8 a;
#pragma unroll
      for (int j = 0; j < 4; ++j) {
        a[j]     = (short)f2bf(x0[j]);
        a[4 + j] = (short)f2bf(x1[j]);
      }
      af[mt] = a;
    }
#pragma unroll
    for (int nt = 0; nt < 4; ++nt)
      bfv[nt] = *reinterpret_cast<const bf16x8*>(Wt + (size_t)(n_base + nt * 16 + lr) * DIN + c);
#pragma unroll
    for (int mt = 0; mt < 4; ++mt)
#pragma unroll
      for (int nt = 0; nt < 4; ++nt)
        acc[mt][nt] = MFMA16(af[mt], bfv[nt], acc[mt][nt]);
  }

#pragma unroll
  for (int nt = 0; nt < 4; ++nt) {
    const int n = n_base + nt * 16 + lr;
#pragma unroll
    for (int mt = 0; mt < 4; ++mt) {
      const int m = m_base + mt * 16 + lg * 4;
      unsigned short b0 = f2bf(acc[mt][nt][0]), b1 = f2bf(acc[mt][nt][1]);
      unsigned short b2 = f2bf(acc[mt][nt][2]), b3 = f2bf(acc[mt][nt][3]);
      uint2v p;
      p[0] = (unsigned)b0 | ((unsigned)b1 << 16);
      p[1] = (unsigned)b2 | ((unsigned)b3 << 16);
      *reinterpret_cast<uint2v*>(xw_t + (size_t)n * NN + m) = p;
    }
  }
}

// ---------------------------------------------------------------------------
// Kernel 2: out[i][n] = (1/deg_i) * sum_j A[i][j] * xw[j][n]
// BM=16, grid 512 (2 blocks/CU), block 512 = 8 waves, wave = 16 rows x 32 cols.
// K-tile = 128 per barrier (64 iters). 3-stage pipeline: global->reg (2-deep)
// -> LDS double buffer. adj converted int32->bf16 at LDS write; deg fused.
// A-tile XOR-swizzled in LDS (block ^= row&7) -> conflict-free b128 reads.
// ---------------------------------------------------------------------------
__global__ __launch_bounds__(512, 4) void k_agg(const int* __restrict__ adj,
                                                const unsigned short* __restrict__ xw_t,
                                                float* __restrict__ out) {
  __shared__ unsigned short As[2][16][128]; // row = 256 B; XOR-swizzled blocks of 8 shorts
  __shared__ float deg_s[16];

  const int tid = threadIdx.x;
  const int w = tid >> 6, l = tid & 63;
  const int lr = l & 15, lg = l >> 4;
  const int row0 = blockIdx.x * 16;

  // staging map: thread -> (row sr, 4 ints at col sc). 16 rows x 32 thr/row.
  const int sr = tid >> 5;
  const int sc = (tid & 31) * 4;
  const int* gsrc = adj + (size_t)(row0 + sr) * NN + sc;

  // swizzled LDS write destination: 4 shorts = half of an 8-short block
  const int wblk = (tid & 31) >> 1;            // block index 0..15
  const int wcol = ((wblk ^ (sr & 7)) << 3) + (tid & 1) * 4;
  unsigned short* wdst0 = &As[0][sr][wcol];
  unsigned short* wdst1 = &As[1][sr][wcol];

  // B fragment bases (direct from global; xw_t is L2-resident)
  const unsigned short* b0base = xw_t + (size_t)(w * 32 + lr) * NN + lg * 8;
  const unsigned short* b1base = b0base + (size_t)16 * NN;

  int cnt = 0;
  f32x4 acc0 = (f32x4)0.0f, acc1 = (f32x4)0.0f;

#define CVT_WRITE(dst, v) do {                                                  \
    cnt += (v)[0] + (v)[1] + (v)[2] + (v)[3];                                   \
    unsigned w0_ = ((0u - (unsigned)(v)[0]) & 0x3F80u) |                        \
                   (((0u - (unsigned)(v)[1]) & 0x3F80u) << 16);                 \
    unsigned w1_ = ((0u - (unsigned)(v)[2]) & 0x3F80u) |                        \
                   (((0u - (unsigned)(v)[3]) & 0x3F80u) << 16);                 \
    uint2v p_; p_[0] = w0_; p_[1] = w1_;                                        \
    *reinterpret_cast<uint2v*>(dst) = p_;                                       \
  } while (0)

#define COMPUTE(buf, it) do {                                                   \
    _Pragma("unroll")                                                           \
    for (int kh_ = 0; kh_ < 4; ++kh_) {                                         \
      const int blk_ = (4 * kh_ + lg) ^ (lr & 7);                               \
      bf16x8 a_  = *reinterpret_cast<const bf16x8*>(&As[buf][lr][blk_ * 8]);    \
      bf16x8 b0_ = *reinterpret_cast<const bf16x8*>(b0base + (it) * 128 + kh_ * 32); \
      bf16x8 b1_ = *reinterpret_cast<const bf16x8*>(b1base + (it) * 128 + kh_ * 32); \
      acc0 = MFMA16(a_, b0_, acc0);                                             \
      acc1 = MFMA16(a_, b1_, acc1);                                             \
    }                                                                           \
  } while (0)

  // prologue: tile0 -> LDS[0]; tile1 -> regs
  int4v gA = *reinterpret_cast<const int4v*>(gsrc);
  CVT_WRITE(wdst0, gA);
  int4v gB = *reinterpret_cast<const int4v*>(gsrc + 128);
  __syncthreads();

  const int NT = NN / 128; // 64
  for (int it = 0; it < NT; it += 2) {
    // even: compute LDS[0], write tile(it+1) -> LDS[1], prefetch tile(it+2)
    if (it + 2 < NT) gA = *reinterpret_cast<const int4v*>(gsrc + (size_t)(it + 2) * 128);
    COMPUTE(0, it);
    CVT_WRITE(wdst1, gB);
    __syncthreads();
    // odd: compute LDS[1], write tile(it+2) -> LDS[0], prefetch tile(it+3)
    if (it + 3 < NT) gB = *reinterpret_cast<const int4v*>(gsrc + (size_t)(it + 3) * 128);
    COMPUTE(1, it + 1);
    if (it + 2 < NT) CVT_WRITE(wdst0, gA);
    __syncthreads();
  }
#undef CVT_WRITE
#undef COMPUTE

  // deg: 32 threads share row sr -> shfl reduce within 32-lane halves
  cnt += __shfl_xor(cnt, 1);
  cnt += __shfl_xor(cnt, 2);
  cnt += __shfl_xor(cnt, 4);
  cnt += __shfl_xor(cnt, 8);
  cnt += __shfl_xor(cnt, 16);
  if ((tid & 31) == 0) deg_s[sr] = (float)cnt;
  __syncthreads();

  float rinv[4];
#pragma unroll
  for (int r = 0; r < 4; ++r) rinv[r] = 1.0f / deg_s[lg * 4 + r];

#pragma unroll
  for (int r = 0; r < 4; ++r) {
    const int row = row0 + lg * 4 + r;
    out[(size_t)row * DOUT + w * 32 + lr]      = acc0[r] * rinv[r];
    out[(size_t)row * DOUT + w * 32 + 16 + lr] = acc1[r] * rinv[r];
  }
}

// ---------------------------------------------------------------------------
extern "C" void kernel_launch(void* const* d_in, const int* in_sizes, int n_in,
                              void* d_out, int out_size, void* d_ws, size_t ws_size,
                              hipStream_t stream) {
  const float* x   = (const float*)d_in[0]; // [8192][512] f32
  const int*   adj = (const int*)d_in[1];   // [8192][8192] i32 (0/1)
  const float* W   = (const float*)d_in[2]; // [512][256] f32
  float* out = (float*)d_out;               // [8192][256] f32

  unsigned short* xw_t = (unsigned short*)d_ws;                                    // 256 x 8192 bf16 (4 MB)
  unsigned short* Wt   = (unsigned short*)((char*)d_ws + (size_t)4 * 1024 * 1024); // 256 x 512 bf16

  k_wt<<<256, 128, 0, stream>>>(W, Wt);
  k_xwt<<<128, 256, 0, stream>>>(x, Wt, xw_t);
  k_agg<<<NN / 16, 512, 0, stream>>>(adj, xw_t, out);
}

// Round 3
// 142.374 us; speedup vs baseline: 2.0475x; 2.0475x over previous
//
#include <hip/hip_runtime.h>
#include <stdint.h>

typedef __attribute__((ext_vector_type(8))) short  bf16x8;
typedef __attribute__((ext_vector_type(4))) float  f32x4;
typedef __attribute__((ext_vector_type(4))) int    int4v;
typedef __attribute__((ext_vector_type(4))) float  float4v;
typedef __attribute__((ext_vector_type(4))) unsigned int uint4v;
typedef __attribute__((ext_vector_type(2))) unsigned int uint2v;

#define NN   8192   // nodes
#define DIN  512
#define DOUT 256

#define BM     64
#define BK     64
#define KSPLIT 4
#define KS     (NN / KSPLIT)   // 2048 per split
#define NT     (KS / BK)       // 32 tiles

#define MFMA16(a, b, c) __builtin_amdgcn_mfma_f32_16x16x32_bf16((a), (b), (c), 0, 0, 0)

__device__ __forceinline__ unsigned short f2bf(float f) {
  unsigned u = __float_as_uint(f);
  return (unsigned short)((u + 0x7FFFu + ((u >> 16) & 1u)) >> 16);
}

// ---------------------------------------------------------------------------
// Kernel 0: Wt[n][c] = bf16(W[c][n]).  W: [512][256] f32 -> Wt: [256][512] bf16
// ---------------------------------------------------------------------------
__global__ void k_wt(const float* __restrict__ W, unsigned short* __restrict__ Wt) {
  int n = blockIdx.x; // 0..255
  for (int c = threadIdx.x; c < DIN; c += blockDim.x)
    Wt[n * DIN + c] = f2bf(W[c * DOUT + n]);
}

// ---------------------------------------------------------------------------
// Kernel 1: xw_t[n][m] = sum_c x[m][c] * W[c][n]   (bf16 out, transposed)
// ---------------------------------------------------------------------------
__global__ __launch_bounds__(256) void k_xwt(const float* __restrict__ x,
                                             const unsigned short* __restrict__ Wt,
                                             unsigned short* __restrict__ xw_t) {
  const int mb = blockIdx.x >> 1, nb = blockIdx.x & 1;
  const int tid = threadIdx.x;
  const int w = tid >> 6, l = tid & 63;
  const int wm = w >> 1, wn = w & 1;
  const int lr = l & 15, lg = l >> 4;
  const int m_base = mb * 128 + wm * 64;
  const int n_base = nb * 128 + wn * 64;

  f32x4 acc[4][4];
  for (int i = 0; i < 4; ++i)
    for (int j = 0; j < 4; ++j) acc[i][j] = (f32x4)0.0f;

  for (int c0 = 0; c0 < DIN; c0 += 32) {
    const int c = c0 + lg * 8;
    bf16x8 af[4], bfv[4];
#pragma unroll
    for (int mt = 0; mt < 4; ++mt) {
      const float* xp = x + (size_t)(m_base + mt * 16 + lr) * DIN + c;
      float4v x0 = *reinterpret_cast<const float4v*>(xp);
      float4v x1 = *reinterpret_cast<const float4v*>(xp + 4);
      bf16x8 a;
#pragma unroll
      for (int j = 0; j < 4; ++j) {
        a[j]     = (short)f2bf(x0[j]);
        a[4 + j] = (short)f2bf(x1[j]);
      }
      af[mt] = a;
    }
#pragma unroll
    for (int nt = 0; nt < 4; ++nt)
      bfv[nt] = *reinterpret_cast<const bf16x8*>(Wt + (size_t)(n_base + nt * 16 + lr) * DIN + c);
#pragma unroll
    for (int mt = 0; mt < 4; ++mt)
#pragma unroll
      for (int nt = 0; nt < 4; ++nt)
        acc[mt][nt] = MFMA16(af[mt], bfv[nt], acc[mt][nt]);
  }

#pragma unroll
  for (int nt = 0; nt < 4; ++nt) {
    const int n = n_base + nt * 16 + lr;
#pragma unroll
    for (int mt = 0; mt < 4; ++mt) {
      const int m = m_base + mt * 16 + lg * 4;
      unsigned short b0 = f2bf(acc[mt][nt][0]), b1 = f2bf(acc[mt][nt][1]);
      unsigned short b2 = f2bf(acc[mt][nt][2]), b3 = f2bf(acc[mt][nt][3]);
      uint2v p;
      p[0] = (unsigned)b0 | ((unsigned)b1 << 16);
      p[1] = (unsigned)b2 | ((unsigned)b3 << 16);
      *reinterpret_cast<uint2v*>(xw_t + (size_t)n * NN + m) = p;
    }
  }
}

// ---------------------------------------------------------------------------
// Kernel 2: split-K partial of  out += A[rows, kslice] * xw[kslice, :]
// BM=64, BN=256(full), BK=64, KSPLIT=4. grid 512, block 256 (4 waves),
// wave = 64m x 64n. K-splits XCD-pinned via bid%8 so each XCD's 1 MB B-slice
// stays L2-resident. B frags register-double-buffered one K-tile ahead.
// adj: global->reg (2 tiles deep) -> LDS double buffer, XOR-swizzled.
// deg partial counts fused; f32 atomics into zeroed out.
// ---------------------------------------------------------------------------
#define PK2(a, b) (((0u - (unsigned)(a)) & 0x3F80u) | (((0u - (unsigned)(b)) & 0x3F80u) << 16))

__global__ __launch_bounds__(256) void k_agg(const int* __restrict__ adj,
                                             const unsigned short* __restrict__ xw_t,
                                             float* __restrict__ out,
                                             int* __restrict__ deg) {
  __shared__ unsigned short As[2][BM][BK]; // 8 KB x2, 8-short blocks XOR-swizzled by row&7

  const int tid = threadIdx.x;
  const int w = tid >> 6, l = tid & 63;
  const int lr = l & 15, lg = l >> 4;

  const int bid = blockIdx.x;
  const int ks = (bid & 7) >> 1;                   // K-split 0..3 (pinned: 2 XCDs per split)
  const int rb = ((bid >> 3) << 1) | (bid & 1);    // row-block 0..127
  const int row0 = rb * BM;
  const int kbase = ks * KS;

  // adj staging: thread -> row sr, 16 ints starting at col c4*16 (contiguous 64 B)
  const int sr = tid >> 2;
  const int c4 = tid & 3;
  const int* gsrc = adj + (size_t)(row0 + sr) * NN + kbase + c4 * 16;

  // swizzled LDS block indices for this thread's two 8-short blocks
  const int b0q = ((c4 * 2) ^ (sr & 7)) * 8;
  const int b1q = ((c4 * 2 + 1) ^ (sr & 7)) * 8;

  // B fragment base: wave w covers n in [w*64, w*64+64)
  const unsigned short* bB = xw_t + (size_t)(w * 64 + lr) * NN + kbase + lg * 8;

  int cnt = 0;
  f32x4 acc[4][4];
#pragma unroll
  for (int i = 0; i < 4; ++i)
#pragma unroll
    for (int j = 0; j < 4; ++j) acc[i][j] = (f32x4)0.0f;

  int4v g0, g1, g2, g3, h0, h1, h2, h3;
  bf16x8 Bc[8], Bn[8]; // [nf*2+kf], statically indexed only

#define LOADG(a, b, c, d, t) do {                                               \
    const int4v* p_ = reinterpret_cast<const int4v*>(gsrc + (size_t)(t) * BK);  \
    a = p_[0]; b = p_[1]; c = p_[2]; d = p_[3];                                 \
  } while (0)

#define LOADB(B, t) do {                                                        \
    _Pragma("unroll")                                                           \
    for (int nf_ = 0; nf_ < 4; ++nf_) {                                         \
      B[nf_ * 2 + 0] = *reinterpret_cast<const bf16x8*>(bB + (size_t)nf_ * 16 * NN + (t) * BK);      \
      B[nf_ * 2 + 1] = *reinterpret_cast<const bf16x8*>(bB + (size_t)nf_ * 16 * NN + (t) * BK + 32); \
    }                                                                           \
  } while (0)

#define CVT_WRITE(buf, a, b, c, d) do {                                         \
    cnt += a[0] + a[1] + a[2] + a[3] + b[0] + b[1] + b[2] + b[3]                \
         + c[0] + c[1] + c[2] + c[3] + d[0] + d[1] + d[2] + d[3];               \
    uint4v q_;                                                                  \
    q_[0] = PK2(a[0], a[1]); q_[1] = PK2(a[2], a[3]);                           \
    q_[2] = PK2(b[0], b[1]); q_[3] = PK2(b[2], b[3]);                           \
    *reinterpret_cast<uint4v*>(&As[buf][sr][b0q]) = q_;                         \
    q_[0] = PK2(c[0], c[1]); q_[1] = PK2(c[2], c[3]);                           \
    q_[2] = PK2(d[0], d[1]); q_[3] = PK2(d[2], d[3]);                           \
    *reinterpret_cast<uint4v*>(&As[buf][sr][b1q]) = q_;                         \
  } while (0)

#define COMPUTE(buf, B) do {                                                    \
    _Pragma("unroll")                                                           \
    for (int kf_ = 0; kf_ < 2; ++kf_) {                                         \
      _Pragma("unroll")                                                         \
      for (int mf_ = 0; mf_ < 4; ++mf_) {                                       \
        const int blk_ = ((kf_ * 4 + lg) ^ (lr & 7)) * 8;                       \
        bf16x8 a_ = *reinterpret_cast<const bf16x8*>(&As[buf][mf_ * 16 + lr][blk_]); \
        acc[mf_][0] = MFMA16(a_, B[0 * 2 + kf_], acc[mf_][0]);                  \
        acc[mf_][1] = MFMA16(a_, B[1 * 2 + kf_], acc[mf_][1]);                  \
        acc[mf_][2] = MFMA16(a_, B[2 * 2 + kf_], acc[mf_][2]);                  \
        acc[mf_][3] = MFMA16(a_, B[3 * 2 + kf_], acc[mf_][3]);                  \
      }                                                                         \
    }                                                                           \
  } while (0)

  // prologue: tile0 adj + B; stage tile0 -> LDS0; tile1 adj -> regs
  LOADG(g0, g1, g2, g3, 0);
  LOADB(Bc, 0);
  CVT_WRITE(0, g0, g1, g2, g3);
  LOADG(h0, h1, h2, h3, 1);
  __syncthreads();

  for (int t = 0; t < NT; t += 2) {
    // even: compute LDS0/Bc; prefetch B(t+1), adj(t+2); stage adj(t+1)->LDS1
    if (t + 1 < NT) LOADB(Bn, t + 1);
    if (t + 2 < NT) LOADG(g0, g1, g2, g3, t + 2);
    COMPUTE(0, Bc);
    if (t + 1 < NT) CVT_WRITE(1, h0, h1, h2, h3);
    __syncthreads();
    if (t + 1 >= NT) break;
    // odd: compute LDS1/Bn; prefetch B(t+2), adj(t+3); stage adj(t+2)->LDS0
    if (t + 2 < NT) LOADB(Bc, t + 2);
    if (t + 3 < NT) LOADG(h0, h1, h2, h3, t + 3);
    COMPUTE(1, Bn);
    if (t + 2 < NT) CVT_WRITE(0, g0, g1, g2, g3);
    __syncthreads();
  }
#undef LOADG
#undef LOADB
#undef CVT_WRITE
#undef COMPUTE

  // deg partial: 4 consecutive lanes (c4=0..3) share row sr
  cnt += __shfl_xor(cnt, 1);
  cnt += __shfl_xor(cnt, 2);
  if ((tid & 3) == 0) atomicAdd(&deg[row0 + sr], cnt);

  // accumulate partial C into out
#pragma unroll
  for (int mf = 0; mf < 4; ++mf)
#pragma unroll
    for (int nf = 0; nf < 4; ++nf)
#pragma unroll
      for (int r = 0; r < 4; ++r) {
        const int row = row0 + mf * 16 + lg * 4 + r;
        const int col = w * 64 + nf * 16 + lr;
        atomicAdd(&out[(size_t)row * DOUT + col], acc[mf][nf][r]);
      }
}

// ---------------------------------------------------------------------------
// Kernel 3: out[i][:] /= deg[i]
// ---------------------------------------------------------------------------
__global__ __launch_bounds__(256) void k_div(float* __restrict__ out,
                                             const int* __restrict__ deg) {
  const int idx = blockIdx.x * 256 + threadIdx.x; // one float4 each
  const int i4 = idx * 4;
  const int row = i4 >> 8; // DOUT=256
  float4v v = *reinterpret_cast<float4v*>(out + i4);
  const float s = 1.0f / (float)deg[row];
  v[0] *= s; v[1] *= s; v[2] *= s; v[3] *= s;
  *reinterpret_cast<float4v*>(out + i4) = v;
}

// ---------------------------------------------------------------------------
extern "C" void kernel_launch(void* const* d_in, const int* in_sizes, int n_in,
                              void* d_out, int out_size, void* d_ws, size_t ws_size,
                              hipStream_t stream) {
  const float* x   = (const float*)d_in[0]; // [8192][512] f32
  const int*   adj = (const int*)d_in[1];   // [8192][8192] i32 (0/1)
  const float* W   = (const float*)d_in[2]; // [512][256] f32
  float* out = (float*)d_out;               // [8192][256] f32

  unsigned short* xw_t = (unsigned short*)d_ws;                                    // 256x8192 bf16 (4 MB)
  unsigned short* Wt   = (unsigned short*)((char*)d_ws + (size_t)4 * 1024 * 1024); // 256x512 bf16 (256 KB)
  int*            deg  = (int*)((char*)d_ws + (size_t)4 * 1024 * 1024 + 256 * 1024); // 8192 i32

  k_wt<<<256, 128, 0, stream>>>(W, Wt);
  k_xwt<<<128, 256, 0, stream>>>(x, Wt, xw_t);
  hipMemsetAsync(out, 0, (size_t)NN * DOUT * sizeof(float), stream);
  hipMemsetAsync(deg, 0, (size_t)NN * sizeof(int), stream);
  k_agg<<<(NN / BM) * KSPLIT, 256, 0, stream>>>(adj, xw_t, out, deg);
  k_div<<<(NN * DOUT) / (256 * 4), 256, 0, stream>>>(out, deg);
}